// Round 5
// baseline (849.176 us; speedup 1.0000x reference)
//
#include <hip/hip_runtime.h>

// Problem dims (fixed by the reference)
#define BB 2
#define LL 1024
#define DI 1536
#define DS 16
#define TPB 256
#define NDBLK (DI / TPB)         // 6 d-blocks
#define NC 64                    // chunks along L
#define CL (LL / NC)             // 16 timesteps per chunk
#define NBLK (NC * NDBLK * BB)   // 768 blocks == 3 per CU
#define FLAG_STRIDE 16           // ints -> 64B per flag line

#define LOG2E 1.44269504088896340736f

__device__ __forceinline__ float exp2_fast(float x) { return __builtin_amdgcn_exp2f(x); }

// ---------------------------------------------------------------------------
// Fused single-pass selective scan with decoupled look-back.
// Block <-> (c, dblk, b); thread <-> d = dblk*256+tid; 16 n-states in regs.
// ws: flags[NBLK] (64B-strided), sdtw[NBLK][256], bsumw[NBLK][16][256],
//     xoutw[NBLK][16][256]   (all d-minor, coalesced)
// Chunk map: x_after = exp2(Av2[n]*sdt) * x_before + Bacc[n]
// ---------------------------------------------------------------------------
__global__ __launch_bounds__(TPB, 3) void ss_fused(
    const float* __restrict__ u, const float* __restrict__ delta,
    const float* __restrict__ A, const float* __restrict__ Bm,
    const float* __restrict__ Cm, const float* __restrict__ Dv,
    int* __restrict__ flags, float* __restrict__ sdtw,
    float* __restrict__ bsumw, float* __restrict__ xoutw,
    float* __restrict__ y)
{
    const int c    = blockIdx.x;              // fastest-varying -> preds dispatched first
    const int dblk = blockIdx.y;
    const int b    = blockIdx.z;
    const int tid  = threadIdx.x;
    const int d    = dblk * TPB + tid;
    const int blk  = (b * NDBLK + dblk) * NC + c;

    float Av2[DS];
    {
        const float4* Ap = (const float4*)(A + (size_t)d * DS);
        #pragma unroll
        for (int q = 0; q < 4; ++q) {
            const float4 av = Ap[q];
            Av2[q*4+0] = av.x * LOG2E; Av2[q*4+1] = av.y * LOG2E;
            Av2[q*4+2] = av.z * LOG2E; Av2[q*4+3] = av.w * LOG2E;
        }
    }

    const size_t bl0 = (size_t)b * LL + (size_t)c * CL;
    const float* __restrict__ dp = delta + bl0 * DI + d;
    const float* __restrict__ up = u     + bl0 * DI + d;
    const float* __restrict__ bp = Bm    + bl0 * DS;   // wave-uniform -> s_load
    const float* __restrict__ cp = Cm    + bl0 * DS;   // wave-uniform -> s_load
    float* __restrict__ yp       = y     + bl0 * DI + d;

    // Burst-load the chunk's dt/uu; they stay in registers for BOTH walks.
    float dt[CL], uu[CL];
    #pragma unroll
    for (int i = 0; i < CL; ++i) {
        dt[i] = dp[(size_t)i * DI];
        uu[i] = up[(size_t)i * DI];
    }

    // ---- Phase A: chunk-local aggregate ----
    float Bacc[DS];
    #pragma unroll
    for (int n = 0; n < DS; ++n) Bacc[n] = 0.0f;
    float sdt = 0.0f;
    #pragma unroll
    for (int i = 0; i < CL; ++i) {
        const float du = dt[i] * uu[i];
        sdt += dt[i];
        const float* __restrict__ bt = bp + i * DS;
        #pragma unroll
        for (int n = 0; n < DS; ++n) {
            const float a = exp2_fast(dt[i] * Av2[n]);
            Bacc[n] = fmaf(a, Bacc[n], du * bt[n]);
        }
    }

    // Publish aggregate (flag=1)
    sdtw[(size_t)blk * TPB + tid] = sdt;
    {
        float* __restrict__ bw = bsumw + (size_t)blk * TPB * DS + tid;
        #pragma unroll
        for (int n = 0; n < DS; ++n) bw[(size_t)n * TPB] = Bacc[n];
    }
    __syncthreads();
    if (tid == 0)
        __hip_atomic_store(&flags[blk * FLAG_STRIDE], 1,
                           __ATOMIC_RELEASE, __HIP_MEMORY_SCOPE_AGENT);

    // ---- Decoupled look-back: resolve incoming state x ----
    float x[DS];
    if (c == 0) {
        #pragma unroll
        for (int n = 0; n < DS; ++n) x[n] = 0.0f;
    } else {
        float Ar[DS], Br[DS];   // running affine map from pred boundary to our start
        #pragma unroll
        for (int n = 0; n < DS; ++n) { Ar[n] = 1.0f; Br[n] = 0.0f; }
        int j = c - 1;
        bool hit = false;
        while (j >= 0) {
            const int pb = blk - (c - j);   // same chain, chunk j
            int f;
            for (;;) {
                f = __hip_atomic_load(&flags[pb * FLAG_STRIDE],
                                      __ATOMIC_RELAXED, __HIP_MEMORY_SCOPE_AGENT);
                if (f != 0) break;
                __builtin_amdgcn_s_sleep(2);
            }
            __threadfence();   // acquire: make pred's data visible
            if (f == 2) {
                const float* __restrict__ xw = xoutw + (size_t)pb * TPB * DS + tid;
                #pragma unroll
                for (int n = 0; n < DS; ++n)
                    x[n] = fmaf(Ar[n], xw[(size_t)n * TPB], Br[n]);
                hit = true;
                break;
            } else {
                const float sdp = sdtw[(size_t)pb * TPB + tid];
                const float* __restrict__ bwj = bsumw + (size_t)pb * TPB * DS + tid;
                #pragma unroll
                for (int n = 0; n < DS; ++n) {
                    const float aj = exp2_fast(Av2[n] * sdp);
                    Br[n] = fmaf(Ar[n], bwj[(size_t)n * TPB], Br[n]);
                    Ar[n] *= aj;
                }
                --j;
            }
        }
        if (!hit) {
            #pragma unroll
            for (int n = 0; n < DS; ++n) x[n] = Br[n];   // reached chain start
        }
    }

    // Publish inclusive prefix EARLY (before the y-walk) to unblock successors
    {
        float* __restrict__ xw = xoutw + (size_t)blk * TPB * DS + tid;
        #pragma unroll
        for (int n = 0; n < DS; ++n) {
            const float atot = exp2_fast(Av2[n] * sdt);
            xw[(size_t)n * TPB] = fmaf(atot, x[n], Bacc[n]);
        }
    }
    __syncthreads();
    if (tid == 0)
        __hip_atomic_store(&flags[blk * FLAG_STRIDE], 2,
                           __ATOMIC_RELEASE, __HIP_MEMORY_SCOPE_AGENT);

    // ---- Phase B: y-walk (dt/uu still in registers) ----
    const float Dd = Dv[d];
    #pragma unroll
    for (int i = 0; i < CL; ++i) {
        const float du = dt[i] * uu[i];
        const float* __restrict__ bt = bp + i * DS;
        const float* __restrict__ ct = cp + i * DS;
        float y0 = 0.0f, y1 = 0.0f;
        #pragma unroll
        for (int n = 0; n < DS; ++n) {
            const float a = exp2_fast(dt[i] * Av2[n]);
            x[n] = fmaf(a, x[n], du * bt[n]);
            if (n & 1) y1 = fmaf(x[n], ct[n], y1);
            else       y0 = fmaf(x[n], ct[n], y0);
        }
        yp[(size_t)i * DI] = fmaf(uu[i], Dd, y0 + y1);
    }
}

// ---------------------------------------------------------------------------
// Fallback 3-kernel path (proven in rounds 2-4), NC-templated
// ---------------------------------------------------------------------------
template <int NCc>
__global__ __launch_bounds__(TPB) void ss1(
    const float* __restrict__ u, const float* __restrict__ delta,
    const float* __restrict__ A, const float* __restrict__ Bm,
    float* __restrict__ sdt_out, float* __restrict__ bsum)
{
    constexpr int CLc = LL / NCc;
    const int d = blockIdx.x * TPB + threadIdx.x;
    const int c = blockIdx.y;
    const int b = blockIdx.z;

    float Av2[DS];
    const float4* Ap = (const float4*)(A + (size_t)d * DS);
    #pragma unroll
    for (int q = 0; q < 4; ++q) {
        const float4 av = Ap[q];
        Av2[q*4+0] = av.x * LOG2E; Av2[q*4+1] = av.y * LOG2E;
        Av2[q*4+2] = av.z * LOG2E; Av2[q*4+3] = av.w * LOG2E;
    }

    const size_t bl0 = (size_t)b * LL + (size_t)c * CLc;
    const float* __restrict__ dp = delta + bl0 * DI + d;
    const float* __restrict__ up = u     + bl0 * DI + d;
    const float* __restrict__ bp = Bm    + bl0 * DS;

    float dt[CLc], uu[CLc];
    #pragma unroll
    for (int i = 0; i < CLc; ++i) {
        dt[i] = dp[(size_t)i * DI];
        uu[i] = up[(size_t)i * DI];
    }

    float Bacc[DS];
    #pragma unroll
    for (int n = 0; n < DS; ++n) Bacc[n] = 0.0f;
    float sdt = 0.0f;

    #pragma unroll
    for (int i = 0; i < CLc; ++i) {
        const float du = dt[i] * uu[i];
        sdt += dt[i];
        const float* __restrict__ bt = bp + i * DS;
        #pragma unroll
        for (int n = 0; n < DS; ++n) {
            const float a = exp2_fast(dt[i] * Av2[n]);
            Bacc[n] = fmaf(a, Bacc[n], du * bt[n]);
        }
    }

    sdt_out[((size_t)c * BB + b) * DI + d] = sdt;
    float* __restrict__ sp = bsum + ((size_t)c * BB + b) * DS * DI + d;
    #pragma unroll
    for (int n = 0; n < DS; ++n) sp[(size_t)n * DI] = Bacc[n];
}

template <int NCc>
__global__ __launch_bounds__(TPB) void ss_scan(
    const float* __restrict__ A,
    const float* __restrict__ sdt_in, const float* __restrict__ bsum,
    float* __restrict__ xin)
{
    const int gid = blockIdx.x * TPB + threadIdx.x;
    const int d   = gid % DI;
    const int bn  = gid / DI;
    const int n   = bn & 15;
    const float Av2 = A[d * DS + n] * LOG2E;

    const size_t cstr = (size_t)BB * DS * DI;
    const size_t sstr = (size_t)BB * DI;
    const size_t soff = (size_t)(bn >> 4) * DI + d;

    float x = 0.0f;
    #pragma unroll 8
    for (int c = 0; c < NCc; ++c) {
        xin[(size_t)c * cstr + gid] = x;
        const float a = exp2_fast(Av2 * sdt_in[(size_t)c * sstr + soff]);
        x = fmaf(a, x, bsum[(size_t)c * cstr + gid]);
    }
}

template <int NCc>
__global__ __launch_bounds__(TPB) void ss2(
    const float* __restrict__ u, const float* __restrict__ delta,
    const float* __restrict__ A, const float* __restrict__ Bm,
    const float* __restrict__ Cm, const float* __restrict__ Dv,
    const float* __restrict__ xin, float* __restrict__ y)
{
    constexpr int CLc = LL / NCc;
    const int d = blockIdx.x * TPB + threadIdx.x;
    const int c = blockIdx.y;
    const int b = blockIdx.z;

    float Av2[DS];
    const float4* Ap = (const float4*)(A + (size_t)d * DS);
    #pragma unroll
    for (int q = 0; q < 4; ++q) {
        const float4 av = Ap[q];
        Av2[q*4+0] = av.x * LOG2E; Av2[q*4+1] = av.y * LOG2E;
        Av2[q*4+2] = av.z * LOG2E; Av2[q*4+3] = av.w * LOG2E;
    }

    float x[DS];
    {
        const float* __restrict__ xp = xin + ((size_t)c * BB + b) * DS * DI + d;
        #pragma unroll
        for (int n = 0; n < DS; ++n) x[n] = xp[(size_t)n * DI];
    }

    const float Dd = Dv[d];
    const size_t bl0 = (size_t)b * LL + (size_t)c * CLc;
    const float* __restrict__ dp = delta + bl0 * DI + d;
    const float* __restrict__ up = u     + bl0 * DI + d;
    const float* __restrict__ bp = Bm    + bl0 * DS;
    const float* __restrict__ cp = Cm    + bl0 * DS;
    float* __restrict__ yp       = y     + bl0 * DI + d;

    float dt[CLc], uu[CLc];
    #pragma unroll
    for (int i = 0; i < CLc; ++i) {
        dt[i] = dp[(size_t)i * DI];
        uu[i] = up[(size_t)i * DI];
    }

    #pragma unroll
    for (int i = 0; i < CLc; ++i) {
        const float du = dt[i] * uu[i];
        const float* __restrict__ bt = bp + i * DS;
        const float* __restrict__ ct = cp + i * DS;
        float y0 = 0.0f, y1 = 0.0f;
        #pragma unroll
        for (int n = 0; n < DS; ++n) {
            const float a = exp2_fast(dt[i] * Av2[n]);
            x[n] = fmaf(a, x[n], du * bt[n]);
            if (n & 1) y1 = fmaf(x[n], ct[n], y1);
            else       y0 = fmaf(x[n], ct[n], y0);
        }
        yp[(size_t)i * DI] = fmaf(uu[i], Dd, y0 + y1);
    }
}

__global__ __launch_bounds__(TPB) void ss_serial(
    const float* __restrict__ u, const float* __restrict__ delta,
    const float* __restrict__ A, const float* __restrict__ Bm,
    const float* __restrict__ Cm, const float* __restrict__ Dv,
    float* __restrict__ y)
{
    const int d = blockIdx.x * TPB + threadIdx.x;
    const int b = blockIdx.z;

    float Av2[DS];
    #pragma unroll
    for (int n = 0; n < DS; ++n) Av2[n] = A[d * DS + n] * LOG2E;

    float x[DS];
    #pragma unroll
    for (int n = 0; n < DS; ++n) x[n] = 0.0f;

    const float Dd = Dv[d];
    const size_t bl0 = (size_t)b * LL;
    const float* __restrict__ dp = delta + bl0 * DI + d;
    const float* __restrict__ up = u     + bl0 * DI + d;
    const float* __restrict__ bp = Bm    + bl0 * DS;
    const float* __restrict__ cp = Cm    + bl0 * DS;
    float* __restrict__ yp       = y     + bl0 * DI + d;

    for (int t = 0; t < LL; ++t) {
        const float dt = dp[(size_t)t * DI];
        const float uu = up[(size_t)t * DI];
        const float du = dt * uu;
        const float* __restrict__ bt = bp + t * DS;
        const float* __restrict__ ct = cp + t * DS;
        float y0 = 0.0f, y1 = 0.0f;
        #pragma unroll
        for (int n = 0; n < DS; ++n) {
            const float a = exp2_fast(dt * Av2[n]);
            x[n] = fmaf(a, x[n], du * bt[n]);
            if (n & 1) y1 = fmaf(x[n], ct[n], y1);
            else       y0 = fmaf(x[n], ct[n], y0);
        }
        yp[(size_t)t * DI] = fmaf(uu, Dd, y0 + y1);
    }
}

extern "C" void kernel_launch(void* const* d_in, const int* in_sizes, int n_in,
                              void* d_out, int out_size, void* d_ws, size_t ws_size,
                              hipStream_t stream) {
    const float* u     = (const float*)d_in[0];
    const float* delta = (const float*)d_in[1];
    const float* A     = (const float*)d_in[2];
    const float* Bm    = (const float*)d_in[3];
    const float* Cm    = (const float*)d_in[4];
    const float* Dv    = (const float*)d_in[5];
    float* y = (float*)d_out;

    // Fused path workspace
    const size_t flags_bytes = (size_t)NBLK * FLAG_STRIDE * sizeof(int);   // 48 KB
    const size_t sdt_bytes   = (size_t)NBLK * TPB * sizeof(float);         // 768 KB
    const size_t bsum_bytes  = (size_t)NBLK * TPB * DS * sizeof(float);    // 12.6 MB
    const size_t fused_need  = flags_bytes + sdt_bytes + 2 * bsum_bytes;   // ~26 MB

    if (ws_size >= fused_need) {
        int*   flags = (int*)d_ws;
        float* sdtw  = (float*)((char*)d_ws + flags_bytes);
        float* bsumw = (float*)((char*)d_ws + flags_bytes + sdt_bytes);
        float* xoutw = (float*)((char*)d_ws + flags_bytes + sdt_bytes + bsum_bytes);

        hipMemsetAsync(flags, 0, flags_bytes, stream);   // graph-capturable node
        dim3 grid(NC, NDBLK, BB);                         // c fastest-varying
        ss_fused<<<grid, TPB, 0, stream>>>(u, delta, A, Bm, Cm, Dv,
                                           flags, sdtw, bsumw, xoutw, y);
        return;
    }

    // Fallback: proven 3-kernel path (NC=64)
    const size_t fb_need = (size_t)64 * BB * DI * sizeof(float)
                         + 2 * (size_t)64 * BB * DI * DS * sizeof(float);
    if (ws_size >= fb_need) {
        float* sdt  = (float*)d_ws;
        float* bsum = (float*)((char*)d_ws + (size_t)64 * BB * DI * sizeof(float));
        float* xin  = (float*)((char*)bsum + (size_t)64 * BB * DI * DS * sizeof(float));

        dim3 grid1(DI / TPB, 64, BB);
        ss1<64><<<grid1, TPB, 0, stream>>>(u, delta, A, Bm, sdt, bsum);
        dim3 gridS((BB * DI * DS) / TPB, 1, 1);
        ss_scan<64><<<gridS, TPB, 0, stream>>>(A, sdt, bsum, xin);
        ss2<64><<<grid1, TPB, 0, stream>>>(u, delta, A, Bm, Cm, Dv, xin, y);
    } else {
        dim3 grid(DI / TPB, 1, BB);
        ss_serial<<<grid, TPB, 0, stream>>>(u, delta, A, Bm, Cm, Dv, y);
    }
}

// Round 6
// 55.677 us; speedup vs baseline: 15.2518x; 15.2518x over previous
//
#include <hip/hip_runtime.h>

// Problem dims (fixed by the reference)
#define BB 2
#define LL 1024
#define DI 1536
#define DS 16
#define TPB 256
#define D2 2                      // d's per thread

#define LOG2E 1.44269504088896340736f

__device__ __forceinline__ float exp2_fast(float x) { return __builtin_amdgcn_exp2f(x); }

// ---------------------------------------------------------------------------
// Pass 1: thread <-> (b, d-pair, chunk); 2 d's x 16 n-states in registers.
// Stores per chunk: sdt (sum of delta, n-independent) and Bacc[n]:
//   x_after = exp2(Av2[n]*sdt) * x_before + Bacc[n]
// Layouts: sdt [c][b][d] (float2 store), bsum [c][b][d][n] (4x float4 per d)
// ---------------------------------------------------------------------------
template <int NCc>
__global__ __launch_bounds__(TPB) void ss1(
    const float* __restrict__ u, const float* __restrict__ delta,
    const float* __restrict__ A, const float* __restrict__ Bm,
    float* __restrict__ sdt_out, float* __restrict__ bsum)
{
    constexpr int CLc = LL / NCc;
    const int d0 = (blockIdx.x * TPB + threadIdx.x) * D2;
    const int c  = blockIdx.y;
    const int b  = blockIdx.z;

    float Av0[DS], Av1[DS];
    {
        const float4* Ap = (const float4*)(A + (size_t)d0 * DS);
        #pragma unroll
        for (int q = 0; q < 4; ++q) {
            const float4 a0 = Ap[q];
            Av0[q*4+0] = a0.x * LOG2E; Av0[q*4+1] = a0.y * LOG2E;
            Av0[q*4+2] = a0.z * LOG2E; Av0[q*4+3] = a0.w * LOG2E;
            const float4 a1 = Ap[q + 4];
            Av1[q*4+0] = a1.x * LOG2E; Av1[q*4+1] = a1.y * LOG2E;
            Av1[q*4+2] = a1.z * LOG2E; Av1[q*4+3] = a1.w * LOG2E;
        }
    }

    const size_t bl0 = (size_t)b * LL + (size_t)c * CLc;
    const float* __restrict__ dp = delta + bl0 * DI + d0;
    const float* __restrict__ up = u     + bl0 * DI + d0;
    const float* __restrict__ bp = Bm    + bl0 * DS;       // wave-uniform -> s_load

    float2 dt[CLc], uu[CLc];
    #pragma unroll
    for (int i = 0; i < CLc; ++i) {
        dt[i] = *(const float2*)(dp + (size_t)i * DI);      // 512B/wave contiguous
        uu[i] = *(const float2*)(up + (size_t)i * DI);
    }

    float B0[DS], B1[DS];
    #pragma unroll
    for (int n = 0; n < DS; ++n) { B0[n] = 0.0f; B1[n] = 0.0f; }
    float s0 = 0.0f, s1 = 0.0f;

    #pragma unroll
    for (int i = 0; i < CLc; ++i) {
        const float du0 = dt[i].x * uu[i].x;
        const float du1 = dt[i].y * uu[i].y;
        s0 += dt[i].x; s1 += dt[i].y;
        const float* __restrict__ bt = bp + i * DS;
        #pragma unroll
        for (int n = 0; n < DS; ++n) {
            const float g = bt[n];
            const float a0 = exp2_fast(dt[i].x * Av0[n]);
            B0[n] = fmaf(a0, B0[n], du0 * g);
            const float a1 = exp2_fast(dt[i].y * Av1[n]);
            B1[n] = fmaf(a1, B1[n], du1 * g);
        }
    }

    *(float2*)(sdt_out + ((size_t)c * BB + b) * DI + d0) = make_float2(s0, s1);
    float4* __restrict__ sp = (float4*)(bsum + (((size_t)c * BB + b) * DI + d0) * DS);
    #pragma unroll
    for (int q = 0; q < 4; ++q)
        sp[q]     = make_float4(B0[q*4+0], B0[q*4+1], B0[q*4+2], B0[q*4+3]);
    #pragma unroll
    for (int q = 0; q < 4; ++q)
        sp[q + 4] = make_float4(B1[q*4+0], B1[q*4+1], B1[q*4+2], B1[q*4+3]);
}

// ---------------------------------------------------------------------------
// Pass 1.5: exclusive scan over chunks per (b,d,n) chain. n-minor layout.
// ---------------------------------------------------------------------------
template <int NCc>
__global__ __launch_bounds__(TPB) void ss_scan(
    const float* __restrict__ A,
    const float* __restrict__ sdt_in, const float* __restrict__ bsum,
    float* __restrict__ xin)
{
    const int gid = blockIdx.x * TPB + threadIdx.x;   // (b*DI+d)*DS+n
    const int bd  = gid >> 4;                          // b*DI + d
    const int d   = bd % DI;
    const int n   = gid & 15;
    const float Av2 = A[d * DS + n] * LOG2E;

    const size_t cstr = (size_t)BB * DI * DS;
    const size_t sstr = (size_t)BB * DI;

    float x = 0.0f;
    #pragma unroll 8
    for (int c = 0; c < NCc; ++c) {
        xin[(size_t)c * cstr + gid] = x;               // state BEFORE chunk c
        const float a = exp2_fast(Av2 * sdt_in[(size_t)c * sstr + bd]);
        x = fmaf(a, x, bsum[(size_t)c * cstr + gid]);
    }
}

// ---------------------------------------------------------------------------
// Pass 2: thread <-> (b, d-pair, chunk); load incoming states, re-run chunk,
// reduce over n in registers, write y as float2.
// ---------------------------------------------------------------------------
template <int NCc>
__global__ __launch_bounds__(TPB) void ss2(
    const float* __restrict__ u, const float* __restrict__ delta,
    const float* __restrict__ A, const float* __restrict__ Bm,
    const float* __restrict__ Cm, const float* __restrict__ Dv,
    const float* __restrict__ xin, float* __restrict__ y)
{
    constexpr int CLc = LL / NCc;
    const int d0 = (blockIdx.x * TPB + threadIdx.x) * D2;
    const int c  = blockIdx.y;
    const int b  = blockIdx.z;

    float Av0[DS], Av1[DS];
    {
        const float4* Ap = (const float4*)(A + (size_t)d0 * DS);
        #pragma unroll
        for (int q = 0; q < 4; ++q) {
            const float4 a0 = Ap[q];
            Av0[q*4+0] = a0.x * LOG2E; Av0[q*4+1] = a0.y * LOG2E;
            Av0[q*4+2] = a0.z * LOG2E; Av0[q*4+3] = a0.w * LOG2E;
            const float4 a1 = Ap[q + 4];
            Av1[q*4+0] = a1.x * LOG2E; Av1[q*4+1] = a1.y * LOG2E;
            Av1[q*4+2] = a1.z * LOG2E; Av1[q*4+3] = a1.w * LOG2E;
        }
    }

    float x0[DS], x1[DS];
    {
        const float4* __restrict__ xp =
            (const float4*)(xin + (((size_t)c * BB + b) * DI + d0) * DS);
        #pragma unroll
        for (int q = 0; q < 4; ++q) {
            const float4 v = xp[q];
            x0[q*4+0] = v.x; x0[q*4+1] = v.y; x0[q*4+2] = v.z; x0[q*4+3] = v.w;
        }
        #pragma unroll
        for (int q = 0; q < 4; ++q) {
            const float4 v = xp[q + 4];
            x1[q*4+0] = v.x; x1[q*4+1] = v.y; x1[q*4+2] = v.z; x1[q*4+3] = v.w;
        }
    }

    const float2 Dd = *(const float2*)(Dv + d0);

    const size_t bl0 = (size_t)b * LL + (size_t)c * CLc;
    const float* __restrict__ dp = delta + bl0 * DI + d0;
    const float* __restrict__ up = u     + bl0 * DI + d0;
    const float* __restrict__ bp = Bm    + bl0 * DS;   // uniform
    const float* __restrict__ cp = Cm    + bl0 * DS;   // uniform
    float* __restrict__ yp       = y     + bl0 * DI + d0;

    float2 dt[CLc], uu[CLc];
    #pragma unroll
    for (int i = 0; i < CLc; ++i) {
        dt[i] = *(const float2*)(dp + (size_t)i * DI);
        uu[i] = *(const float2*)(up + (size_t)i * DI);
    }

    #pragma unroll
    for (int i = 0; i < CLc; ++i) {
        const float du0 = dt[i].x * uu[i].x;
        const float du1 = dt[i].y * uu[i].y;
        const float* __restrict__ bt = bp + i * DS;
        const float* __restrict__ ct = cp + i * DS;
        float ya0 = 0.0f, yb0 = 0.0f, ya1 = 0.0f, yb1 = 0.0f;
        #pragma unroll
        for (int n = 0; n < DS; ++n) {
            const float g = bt[n];
            const float cv = ct[n];
            const float a0 = exp2_fast(dt[i].x * Av0[n]);
            x0[n] = fmaf(a0, x0[n], du0 * g);
            const float a1 = exp2_fast(dt[i].y * Av1[n]);
            x1[n] = fmaf(a1, x1[n], du1 * g);
            if (n & 1) { yb0 = fmaf(x0[n], cv, yb0); yb1 = fmaf(x1[n], cv, yb1); }
            else       { ya0 = fmaf(x0[n], cv, ya0); ya1 = fmaf(x1[n], cv, ya1); }
        }
        const float2 out = make_float2(fmaf(uu[i].x, Dd.x, ya0 + yb0),
                                       fmaf(uu[i].y, Dd.y, ya1 + yb1));
        *(float2*)(yp + (size_t)i * DI) = out;
    }
}

// Fallback: streaming serial scan (no workspace needed)
__global__ __launch_bounds__(TPB) void ss_serial(
    const float* __restrict__ u, const float* __restrict__ delta,
    const float* __restrict__ A, const float* __restrict__ Bm,
    const float* __restrict__ Cm, const float* __restrict__ Dv,
    float* __restrict__ y)
{
    const int d = blockIdx.x * TPB + threadIdx.x;
    const int b = blockIdx.z;

    float Av2[DS];
    #pragma unroll
    for (int n = 0; n < DS; ++n) Av2[n] = A[d * DS + n] * LOG2E;

    float x[DS];
    #pragma unroll
    for (int n = 0; n < DS; ++n) x[n] = 0.0f;

    const float Dd = Dv[d];
    const size_t bl0 = (size_t)b * LL;
    const float* __restrict__ dp = delta + bl0 * DI + d;
    const float* __restrict__ up = u     + bl0 * DI + d;
    const float* __restrict__ bp = Bm    + bl0 * DS;
    const float* __restrict__ cp = Cm    + bl0 * DS;
    float* __restrict__ yp       = y     + bl0 * DI + d;

    for (int t = 0; t < LL; ++t) {
        const float dt = dp[(size_t)t * DI];
        const float uu = up[(size_t)t * DI];
        const float du = dt * uu;
        const float* __restrict__ bt = bp + t * DS;
        const float* __restrict__ ct = cp + t * DS;
        float y0 = 0.0f, y1 = 0.0f;
        #pragma unroll
        for (int n = 0; n < DS; ++n) {
            const float a = exp2_fast(dt * Av2[n]);
            x[n] = fmaf(a, x[n], du * bt[n]);
            if (n & 1) y1 = fmaf(x[n], ct[n], y1);
            else       y0 = fmaf(x[n], ct[n], y0);
        }
        yp[(size_t)t * DI] = fmaf(uu, Dd, y0 + y1);
    }
}

template <int NCc>
static void launch_chunked(const float* u, const float* delta, const float* A,
                           const float* Bm, const float* Cm, const float* Dv,
                           float* y, void* d_ws, hipStream_t stream) {
    const size_t sdt_bytes  = (size_t)NCc * BB * DI * sizeof(float);
    const size_t bsum_bytes = (size_t)NCc * BB * DI * DS * sizeof(float);

    float* sdt  = (float*)d_ws;
    float* bsum = (float*)((char*)d_ws + sdt_bytes);
    float* xin  = (float*)((char*)d_ws + sdt_bytes + bsum_bytes);

    dim3 grid1(DI / (TPB * D2), NCc, BB);
    ss1<NCc><<<grid1, TPB, 0, stream>>>(u, delta, A, Bm, sdt, bsum);

    dim3 gridS((BB * DI * DS) / TPB, 1, 1);
    ss_scan<NCc><<<gridS, TPB, 0, stream>>>(A, sdt, bsum, xin);

    ss2<NCc><<<grid1, TPB, 0, stream>>>(u, delta, A, Bm, Cm, Dv, xin, y);
}

extern "C" void kernel_launch(void* const* d_in, const int* in_sizes, int n_in,
                              void* d_out, int out_size, void* d_ws, size_t ws_size,
                              hipStream_t stream) {
    const float* u     = (const float*)d_in[0];
    const float* delta = (const float*)d_in[1];
    const float* A     = (const float*)d_in[2];
    const float* Bm    = (const float*)d_in[3];
    const float* Cm    = (const float*)d_in[4];
    const float* Dv    = (const float*)d_in[5];
    float* y = (float*)d_out;

    auto need = [](int nc) {
        return (size_t)nc * BB * DI * sizeof(float) +            // sdt
               2 * (size_t)nc * BB * DI * DS * sizeof(float);    // bsum + xin
    };

    if (ws_size >= need(128)) {
        launch_chunked<128>(u, delta, A, Bm, Cm, Dv, y, d_ws, stream);
    } else if (ws_size >= need(64)) {
        launch_chunked<64>(u, delta, A, Bm, Cm, Dv, y, d_ws, stream);
    } else {
        dim3 grid(DI / TPB, 1, BB);
        ss_serial<<<grid, TPB, 0, stream>>>(u, delta, A, Bm, Cm, Dv, y);
    }
}